// Round 2
// baseline (491.092 us; speedup 1.0000x reference)
//
#include <hip/hip_runtime.h>
#include <hip/hip_bf16.h>

#define BDIM 1024
#define LDIM 128
#define KDIM 16
#define DDIM 512
#define NFEAT 100000
#define NLAB 131072
#define NNEG 2048
#define NPOS (BDIM * KDIM)      /* 16384 */
#define NSUB (NPOS + NNEG)      /* 18432 */
#define EPSV 0.1f
#define CV 2.1f

// ---------------- init: head=-1, zero accumulators ----------------
__global__ __launch_bounds__(256) void init_kernel(int* __restrict__ head,
                                                   float* __restrict__ Zrow,
                                                   float* __restrict__ accum) {
    int j = blockIdx.x * 256 + threadIdx.x;   // grid covers NLAB
    head[j] = -1;
    if (j < BDIM) Zrow[j] = 0.f;
    if (j < 2) accum[j] = 0.f;
}

// ---------------- link: all_idx + inverse map (handles duplicate labels) ----------------
__global__ __launch_bounds__(256) void link_kernel(const int* __restrict__ labels,
                                                   const int* __restrict__ negs,
                                                   int* __restrict__ all_idx,
                                                   int* __restrict__ head,
                                                   int* __restrict__ nxt) {
    int j = blockIdx.x * 256 + threadIdx.x;
    if (j >= NSUB) return;
    int v = (j < NPOS) ? max(labels[j], 0) : negs[j - NPOS];
    all_idx[j] = v;
    nxt[j] = atomicExch(&head[v], j);
}

// ---------------- query: embed gather-sum + normalize ----------------
__global__ __launch_bounds__(256) void query_kernel(const int* __restrict__ indices,
                                                    const float* __restrict__ mask,
                                                    const float* __restrict__ embed,
                                                    float* __restrict__ query) {
    __shared__ int   sidx[LDIM];
    __shared__ float smask[LDIM];
    int b = blockIdx.x;
    int t = threadIdx.x;
    if (t < LDIM) {
        sidx[t]  = indices[b * LDIM + t];
        smask[t] = mask[b * LDIM + t];
    }
    __syncthreads();

    float ax = 0.f, ay = 0.f, msum = 0.f;
    #pragma unroll 2
    for (int l = 0; l < LDIM; l += 2) {
        int   i0 = sidx[l],   i1 = sidx[l + 1];
        float m0 = smask[l],  m1 = smask[l + 1];
        float2 r0 = *(const float2*)&embed[(size_t)i0 * DDIM + t * 2];
        float2 r1 = *(const float2*)&embed[(size_t)i1 * DDIM + t * 2];
        msum += m0 + m1;
        ax += m0 * r0.x + m1 * r1.x;
        ay += m0 * r0.y + m1 * r1.y;
    }
    float denom = fmaxf(msum, 1.0f);
    ax /= denom; ay /= denom;

    float ss = ax * ax + ay * ay;
    #pragma unroll
    for (int off = 32; off > 0; off >>= 1) ss += __shfl_down(ss, off, 64);
    __shared__ float red[4];
    __shared__ float snorm;
    int wid = t >> 6, lane = t & 63;
    if (lane == 0) red[wid] = ss;
    __syncthreads();
    if (t == 0) snorm = sqrtf(red[0] + red[1] + red[2] + red[3]);
    __syncthreads();
    float inv = 1.f / fmaxf(snorm, 1e-4f);
    float2 o = { ax * inv, ay * inv };
    *(float2*)&query[(size_t)b * DDIM + t * 2] = o;
}

// ---------------- W stream-scatter: WsubT[d][j] = Wk[d][all_idx[j]] ----------------
__global__ __launch_bounds__(256) void wscatter_kernel(const float* __restrict__ Wk,
                                                       const int* __restrict__ head,
                                                       const int* __restrict__ nxt,
                                                       float* __restrict__ WsubT) {
    int d   = blockIdx.x;          // 512
    int seg = blockIdx.y;          // 0..1 (same XCD as its sibling: stride 512 ≡ 0 mod 8)
    const float* row  = Wk    + (size_t)d * NLAB;
    float*       orow = WsubT + (size_t)d * NSUB;
    int base = seg * (NLAB / 2);
    int end  = base + (NLAB / 2);
    for (int v = base + threadIdx.x * 4; v < end; v += 256 * 4) {
        float4 w = *(const float4*)&row[v];
        int4   h = *(const int4*)&head[v];
        if (h.x >= 0) { for (int j = h.x; j >= 0; j = nxt[j]) orow[j] = w.x; }
        if (h.y >= 0) { for (int j = h.y; j >= 0; j = nxt[j]) orow[j] = w.y; }
        if (h.z >= 0) { for (int j = h.z; j >= 0; j = nxt[j]) orow[j] = w.z; }
        if (h.w >= 0) { for (int j = h.w; j >= 0; j = nxt[j]) orow[j] = w.w; }
    }
}

// ---------------- column norms of WsubT ----------------
__global__ __launch_bounds__(256) void norms_kernel(const float* __restrict__ WsubT,
                                                    float* __restrict__ norms) {
    int j = blockIdx.x * 256 + threadIdx.x;
    if (j >= NSUB) return;
    float s = 0.f;
    for (int d = 0; d < DDIM; ++d) {
        float v = WsubT[(size_t)d * NSUB + j];
        s += v * v;
    }
    norms[j] = sqrtf(s);
}

// ---------------- positive scores (diagonal block) ----------------
__global__ __launch_bounds__(256) void pos_kernel(const float* __restrict__ query,
                                                  const float* __restrict__ WsubT,
                                                  const float* __restrict__ norms,
                                                  float* __restrict__ pos_scores,
                                                  float* __restrict__ Zrow) {
    int j = blockIdx.x * 256 + threadIdx.x;   // 0..NPOS
    int b = j >> 4;
    const float* q = query + (size_t)b * DDIM;
    float acc = 0.f;
    #pragma unroll 4
    for (int d = 0; d < DDIM; ++d) acc += q[d] * WsubT[(size_t)d * NSUB + j];
    float dot = acc / fmaxf(norms[j], 1e-4f);
    dot = fminf(fmaxf(dot, -0.999f), 0.999f);
    float sc = dot * dot / fmaxf(CV - 2.f * dot, EPSV);
    pos_scores[j] = sc;
    atomicAdd(&Zrow[b], sc);
}

// ---------------- negative GEMM + fused score + row-sum ----------------
#define BM 64
#define BN 64
#define BK 32
__global__ __launch_bounds__(256) void neg_kernel(const float* __restrict__ query,
                                                  const float* __restrict__ WsubT,
                                                  const float* __restrict__ norms,
                                                  float* __restrict__ Zrow) {
    __shared__ float As[BK][BM + 1];
    __shared__ float Bs[BK][BN];
    __shared__ float rowsum[BM];
    int t = threadIdx.x;
    int bm0 = blockIdx.x * BM;
    int nb0 = blockIdx.y * BN;
    int tx = t & 15, ty = t >> 4;
    float c[4][4] = {{0.f}};

    int ar = t >> 3;            // 0..31
    int ak = (t & 7) * 4;       // 0..28
    int bk = t >> 4;            // 0..15
    int bn = (t & 15) * 4;      // 0..60

    for (int k0 = 0; k0 < DDIM; k0 += BK) {
        float4 a0 = *(const float4*)&query[(size_t)(bm0 + ar)      * DDIM + k0 + ak];
        float4 a1 = *(const float4*)&query[(size_t)(bm0 + ar + 32) * DDIM + k0 + ak];
        float4 b0 = *(const float4*)&WsubT[(size_t)(k0 + bk)      * NSUB + NPOS + nb0 + bn];
        float4 b1 = *(const float4*)&WsubT[(size_t)(k0 + bk + 16) * NSUB + NPOS + nb0 + bn];
        __syncthreads();
        As[ak + 0][ar] = a0.x; As[ak + 1][ar] = a0.y; As[ak + 2][ar] = a0.z; As[ak + 3][ar] = a0.w;
        As[ak + 0][ar + 32] = a1.x; As[ak + 1][ar + 32] = a1.y; As[ak + 2][ar + 32] = a1.z; As[ak + 3][ar + 32] = a1.w;
        *(float4*)&Bs[bk][bn]      = b0;
        *(float4*)&Bs[bk + 16][bn] = b1;
        __syncthreads();
        #pragma unroll
        for (int kk = 0; kk < BK; ++kk) {
            float av[4], bv[4];
            #pragma unroll
            for (int i = 0; i < 4; ++i) av[i] = As[kk][ty * 4 + i];
            #pragma unroll
            for (int i = 0; i < 4; ++i) bv[i] = Bs[kk][tx * 4 + i];
            #pragma unroll
            for (int i = 0; i < 4; ++i)
                #pragma unroll
                for (int jn = 0; jn < 4; ++jn)
                    c[i][jn] += av[i] * bv[jn];
        }
    }

    float nrm[4];
    #pragma unroll
    for (int jn = 0; jn < 4; ++jn) nrm[jn] = fmaxf(norms[NPOS + nb0 + tx * 4 + jn], 1e-4f);

    __syncthreads();
    if (t < BM) rowsum[t] = 0.f;
    __syncthreads();
    #pragma unroll
    for (int i = 0; i < 4; ++i) {
        float s = 0.f;
        #pragma unroll
        for (int jn = 0; jn < 4; ++jn) {
            float dot = c[i][jn] / nrm[jn];
            dot = fminf(fmaxf(dot, -0.999f), 0.999f);
            s += dot * dot / fmaxf(CV - 2.f * dot, EPSV);
        }
        atomicAdd(&rowsum[ty * 4 + i], s);
    }
    __syncthreads();
    if (t < BM) atomicAdd(&Zrow[bm0 + t], rowsum[t]);
}

// ---------------- finalize ----------------
__global__ __launch_bounds__(256) void finalize_kernel(const float* __restrict__ pos_scores,
                                                       const float* __restrict__ label_mask,
                                                       const float* __restrict__ Zrow,
                                                       float* __restrict__ accum) {
    int j = blockIdx.x * 256 + threadIdx.x;  // < NPOS
    int b = j >> 4;
    float lm = label_mask[j];
    float logZ = logf(Zrow[b] + (float)(KDIM + NNEG) * 1e-8f);
    float v = lm * (logf(pos_scores[j] + 1e-8f) - logZ);
    #pragma unroll
    for (int off = 32; off > 0; off >>= 1) {
        v  += __shfl_down(v, off, 64);
        lm += __shfl_down(lm, off, 64);
    }
    __shared__ float rv[4], rl[4];
    int wid = threadIdx.x >> 6, lane = threadIdx.x & 63;
    if (lane == 0) { rv[wid] = v; rl[wid] = lm; }
    __syncthreads();
    if (threadIdx.x == 0) {
        atomicAdd(&accum[0], rv[0] + rv[1] + rv[2] + rv[3]);
        atomicAdd(&accum[1], rl[0] + rl[1] + rl[2] + rl[3]);
    }
}

__global__ void writeout_kernel(const float* __restrict__ accum, float* __restrict__ out) {
    out[0] = -accum[0] / (accum[1] + 1e-6f);
}

extern "C" void kernel_launch(void* const* d_in, const int* in_sizes, int n_in,
                              void* d_out, int out_size, void* d_ws, size_t ws_size,
                              hipStream_t stream) {
    const int*   indices    = (const int*)  d_in[0];
    const float* mask       = (const float*)d_in[1];
    const int*   labels     = (const int*)  d_in[2];
    const float* label_mask = (const float*)d_in[3];
    const int*   negs       = (const int*)  d_in[4];
    const float* embed      = (const float*)d_in[5];
    const float* Wk         = (const float*)d_in[6];
    float* out = (float*)d_out;

    // workspace layout
    float* WsubT      = (float*)d_ws;                           // 512*18432 f32
    float* query      = WsubT + (size_t)DDIM * NSUB;            // 1024*512 f32
    int*   all_idx    = (int*)(query + (size_t)BDIM * DDIM);    // NSUB
    float* norms      = (float*)(all_idx + NSUB);               // NSUB
    float* pos_scores = norms + NSUB;                           // NPOS
    float* Zrow       = pos_scores + NPOS;                      // BDIM
    float* accum      = Zrow + BDIM;                            // 2
    int*   head       = (int*)(accum + 2);                      // NLAB
    int*   nxt        = head + NLAB;                            // NSUB

    init_kernel<<<NLAB / 256, 256, 0, stream>>>(head, Zrow, accum);
    link_kernel<<<(NSUB + 255) / 256, 256, 0, stream>>>(labels, negs, all_idx, head, nxt);
    query_kernel<<<BDIM, 256, 0, stream>>>(indices, mask, embed, query);
    wscatter_kernel<<<dim3(DDIM, 2), 256, 0, stream>>>(Wk, head, nxt, WsubT);
    norms_kernel<<<NSUB / 256, 256, 0, stream>>>(WsubT, norms);
    pos_kernel<<<NPOS / 256, 256, 0, stream>>>(query, WsubT, norms, pos_scores, Zrow);
    neg_kernel<<<dim3(BDIM / BM, NNEG / BN), 256, 0, stream>>>(query, WsubT, norms, Zrow);
    finalize_kernel<<<NPOS / 256, 256, 0, stream>>>(pos_scores, label_mask, Zrow, accum);
    writeout_kernel<<<1, 1, 0, stream>>>(accum, out);
}

// Round 3
// 270.991 us; speedup vs baseline: 1.8122x; 1.8122x over previous
//
#include <hip/hip_runtime.h>
#include <hip/hip_bf16.h>

#define BDIM 1024
#define LDIM 128
#define KDIM 16
#define DDIM 512
#define NFEAT 100000
#define NLAB 131072
#define NNEG 2048
#define NPOS (BDIM * KDIM)      /* 16384 */
#define NSUB (NPOS + NNEG)      /* 18432 */
#define EPSV 0.1f
#define CV 2.1f

// ---------------- init: zero cnt, Zrow, accum ----------------
__global__ __launch_bounds__(256) void init_kernel(int* __restrict__ cnt,
                                                   float* __restrict__ Zrow,
                                                   float* __restrict__ accum) {
    int j = blockIdx.x * 256 + threadIdx.x;   // grid covers NLAB
    cnt[j] = 0;
    if (j < BDIM) Zrow[j] = 0.f;
    if (j < 2) accum[j] = 0.f;
}

// ---------------- count: all_idx + histogram ----------------
__global__ __launch_bounds__(256) void count_kernel(const int* __restrict__ labels,
                                                    const int* __restrict__ negs,
                                                    int* __restrict__ all_idx,
                                                    int* __restrict__ cnt) {
    int j = blockIdx.x * 256 + threadIdx.x;
    if (j >= NSUB) return;
    int v = (j < NPOS) ? max(labels[j], 0) : negs[j - NPOS];
    all_idx[j] = v;
    atomicAdd(&cnt[v], 1);
}

// ---------------- scan1: per-block exclusive scan of 512 counts ----------------
__global__ __launch_bounds__(256) void scan1_kernel(const int* __restrict__ cnt,
                                                    int* __restrict__ offs,
                                                    int* __restrict__ bsum) {
    int t = threadIdx.x;
    int base = blockIdx.x * 512;
    int a0 = cnt[base + 2 * t], a1 = cnt[base + 2 * t + 1];
    int chunk = a0 + a1;
    int ts = chunk;
    int lane = t & 63, wid = t >> 6;
    #pragma unroll
    for (int off = 1; off < 64; off <<= 1) {
        int v = __shfl_up(ts, off, 64);
        if (lane >= off) ts += v;
    }
    __shared__ int wsum[4];
    if (lane == 63) wsum[wid] = ts;
    __syncthreads();
    int woff = 0;
    for (int w = 0; w < wid; ++w) woff += wsum[w];
    int incl = woff + ts;              // inclusive over thread-chunks
    int excl = incl - chunk;
    offs[base + 2 * t]     = excl;
    offs[base + 2 * t + 1] = excl + a0;
    if (t == 255) bsum[blockIdx.x] = incl;
}

// ---------------- scan2: exclusive scan of 256 block sums ----------------
__global__ __launch_bounds__(256) void scan2_kernel(const int* __restrict__ bsum,
                                                    int* __restrict__ bofs) {
    int t = threadIdx.x;
    int a = bsum[t];
    int ts = a;
    int lane = t & 63, wid = t >> 6;
    #pragma unroll
    for (int off = 1; off < 64; off <<= 1) {
        int v = __shfl_up(ts, off, 64);
        if (lane >= off) ts += v;
    }
    __shared__ int wsum[4];
    if (lane == 63) wsum[wid] = ts;
    __syncthreads();
    int woff = 0;
    for (int w = 0; w < wid; ++w) woff += wsum[w];
    bofs[t] = woff + ts - a;
}

// ---------------- scan3: add block offsets ----------------
__global__ __launch_bounds__(256) void scan3_kernel(int* __restrict__ offs,
                                                    const int* __restrict__ bofs) {
    int v = blockIdx.x * 256 + threadIdx.x;   // grid covers NLAB
    offs[v] += bofs[v >> 9];
}

// ---------------- place: sorted order + rank ----------------
__global__ __launch_bounds__(256) void place_kernel(const int* __restrict__ all_idx,
                                                    int* __restrict__ offs,
                                                    int* __restrict__ srt_v,
                                                    int* __restrict__ rank) {
    int j = blockIdx.x * 256 + threadIdx.x;
    if (j >= NSUB) return;
    int v = all_idx[j];
    int r = atomicAdd(&offs[v], 1);
    srt_v[r] = v;
    rank[j] = r;
}

// ---------------- query: embed gather-sum + normalize ----------------
__global__ __launch_bounds__(256) void query_kernel(const int* __restrict__ indices,
                                                    const float* __restrict__ mask,
                                                    const float* __restrict__ embed,
                                                    float* __restrict__ query) {
    __shared__ int   sidx[LDIM];
    __shared__ float smask[LDIM];
    int b = blockIdx.x;
    int t = threadIdx.x;
    if (t < LDIM) {
        sidx[t]  = indices[b * LDIM + t];
        smask[t] = mask[b * LDIM + t];
    }
    __syncthreads();

    float ax = 0.f, ay = 0.f, msum = 0.f;
    #pragma unroll 2
    for (int l = 0; l < LDIM; l += 2) {
        int   i0 = sidx[l],   i1 = sidx[l + 1];
        float m0 = smask[l],  m1 = smask[l + 1];
        float2 r0 = *(const float2*)&embed[(size_t)i0 * DDIM + t * 2];
        float2 r1 = *(const float2*)&embed[(size_t)i1 * DDIM + t * 2];
        msum += m0 + m1;
        ax += m0 * r0.x + m1 * r1.x;
        ay += m0 * r0.y + m1 * r1.y;
    }
    float denom = fmaxf(msum, 1.0f);
    ax /= denom; ay /= denom;

    float ss = ax * ax + ay * ay;
    #pragma unroll
    for (int off = 32; off > 0; off >>= 1) ss += __shfl_down(ss, off, 64);
    __shared__ float red[4];
    __shared__ float snorm;
    int wid = t >> 6, lane = t & 63;
    if (lane == 0) red[wid] = ss;
    __syncthreads();
    if (t == 0) snorm = sqrtf(red[0] + red[1] + red[2] + red[3]);
    __syncthreads();
    float inv = 1.f / fmaxf(snorm, 1e-4f);
    float2 o = { ax * inv, ay * inv };
    *(float2*)&query[(size_t)b * DDIM + t * 2] = o;
}

// ---------------- gather: Wsrt[d][r] = Wk[d][srt_v[r]] (ascending reads, coalesced writes) ----------------
__global__ __launch_bounds__(256) void gather_kernel(const float* __restrict__ Wk,
                                                     const int* __restrict__ srt_v,
                                                     float* __restrict__ Wsrt) {
    int d = blockIdx.x;
    const float* row = Wk   + (size_t)d * NLAB;
    float*       o   = Wsrt + (size_t)d * NSUB;
    #pragma unroll 4
    for (int r = threadIdx.x; r < NSUB; r += 256) {
        int v = srt_v[r];
        o[r] = __builtin_nontemporal_load(&row[v]);
    }
}

// ---------------- permute: WsubT[d][j] = Wsrt[d][rank[j]] ----------------
__global__ __launch_bounds__(256) void permute_kernel(const float* __restrict__ Wsrt,
                                                      const int* __restrict__ rank,
                                                      float* __restrict__ WsubT) {
    int d = blockIdx.x;
    const float* src = Wsrt  + (size_t)d * NSUB;
    float*       dst = WsubT + (size_t)d * NSUB;
    #pragma unroll 4
    for (int j = threadIdx.x; j < NSUB; j += 256)
        dst[j] = src[rank[j]];
}

// ---------------- column norms of WsubT ----------------
__global__ __launch_bounds__(256) void norms_kernel(const float* __restrict__ WsubT,
                                                    float* __restrict__ norms) {
    int j = blockIdx.x * 256 + threadIdx.x;
    if (j >= NSUB) return;
    float s = 0.f;
    for (int d = 0; d < DDIM; ++d) {
        float v = WsubT[(size_t)d * NSUB + j];
        s += v * v;
    }
    norms[j] = sqrtf(s);
}

// ---------------- positive scores (diagonal block) ----------------
__global__ __launch_bounds__(256) void pos_kernel(const float* __restrict__ query,
                                                  const float* __restrict__ WsubT,
                                                  const float* __restrict__ norms,
                                                  float* __restrict__ pos_scores,
                                                  float* __restrict__ Zrow) {
    int j = blockIdx.x * 256 + threadIdx.x;   // 0..NPOS
    int b = j >> 4;
    const float* q = query + (size_t)b * DDIM;
    float acc = 0.f;
    #pragma unroll 4
    for (int d = 0; d < DDIM; ++d) acc += q[d] * WsubT[(size_t)d * NSUB + j];
    float dot = acc / fmaxf(norms[j], 1e-4f);
    dot = fminf(fmaxf(dot, -0.999f), 0.999f);
    float sc = dot * dot / fmaxf(CV - 2.f * dot, EPSV);
    pos_scores[j] = sc;
    atomicAdd(&Zrow[b], sc);
}

// ---------------- negative GEMM + fused score + row-sum ----------------
#define BM 64
#define BN 64
#define BK 32
__global__ __launch_bounds__(256) void neg_kernel(const float* __restrict__ query,
                                                  const float* __restrict__ WsubT,
                                                  const float* __restrict__ norms,
                                                  float* __restrict__ Zrow) {
    __shared__ float As[BK][BM + 1];
    __shared__ float Bs[BK][BN];
    __shared__ float rowsum[BM];
    int t = threadIdx.x;
    int bm0 = blockIdx.x * BM;
    int nb0 = blockIdx.y * BN;
    int tx = t & 15, ty = t >> 4;
    float c[4][4] = {{0.f}};

    int ar = t >> 3;            // 0..31
    int ak = (t & 7) * 4;       // 0..28
    int bk = t >> 4;            // 0..15
    int bn = (t & 15) * 4;      // 0..60

    for (int k0 = 0; k0 < DDIM; k0 += BK) {
        float4 a0 = *(const float4*)&query[(size_t)(bm0 + ar)      * DDIM + k0 + ak];
        float4 a1 = *(const float4*)&query[(size_t)(bm0 + ar + 32) * DDIM + k0 + ak];
        float4 b0 = *(const float4*)&WsubT[(size_t)(k0 + bk)      * NSUB + NPOS + nb0 + bn];
        float4 b1 = *(const float4*)&WsubT[(size_t)(k0 + bk + 16) * NSUB + NPOS + nb0 + bn];
        __syncthreads();
        As[ak + 0][ar] = a0.x; As[ak + 1][ar] = a0.y; As[ak + 2][ar] = a0.z; As[ak + 3][ar] = a0.w;
        As[ak + 0][ar + 32] = a1.x; As[ak + 1][ar + 32] = a1.y; As[ak + 2][ar + 32] = a1.z; As[ak + 3][ar + 32] = a1.w;
        *(float4*)&Bs[bk][bn]      = b0;
        *(float4*)&Bs[bk + 16][bn] = b1;
        __syncthreads();
        #pragma unroll
        for (int kk = 0; kk < BK; ++kk) {
            float av[4], bv[4];
            #pragma unroll
            for (int i = 0; i < 4; ++i) av[i] = As[kk][ty * 4 + i];
            #pragma unroll
            for (int i = 0; i < 4; ++i) bv[i] = Bs[kk][tx * 4 + i];
            #pragma unroll
            for (int i = 0; i < 4; ++i)
                #pragma unroll
                for (int jn = 0; jn < 4; ++jn)
                    c[i][jn] += av[i] * bv[jn];
        }
    }

    float nrm[4];
    #pragma unroll
    for (int jn = 0; jn < 4; ++jn) nrm[jn] = fmaxf(norms[NPOS + nb0 + tx * 4 + jn], 1e-4f);

    __syncthreads();
    if (t < BM) rowsum[t] = 0.f;
    __syncthreads();
    #pragma unroll
    for (int i = 0; i < 4; ++i) {
        float s = 0.f;
        #pragma unroll
        for (int jn = 0; jn < 4; ++jn) {
            float dot = c[i][jn] / nrm[jn];
            dot = fminf(fmaxf(dot, -0.999f), 0.999f);
            s += dot * dot / fmaxf(CV - 2.f * dot, EPSV);
        }
        atomicAdd(&rowsum[ty * 4 + i], s);
    }
    __syncthreads();
    if (t < BM) atomicAdd(&Zrow[bm0 + t], rowsum[t]);
}

// ---------------- finalize ----------------
__global__ __launch_bounds__(256) void finalize_kernel(const float* __restrict__ pos_scores,
                                                       const float* __restrict__ label_mask,
                                                       const float* __restrict__ Zrow,
                                                       float* __restrict__ accum) {
    int j = blockIdx.x * 256 + threadIdx.x;  // < NPOS
    int b = j >> 4;
    float lm = label_mask[j];
    float logZ = logf(Zrow[b] + (float)(KDIM + NNEG) * 1e-8f);
    float v = lm * (logf(pos_scores[j] + 1e-8f) - logZ);
    #pragma unroll
    for (int off = 32; off > 0; off >>= 1) {
        v  += __shfl_down(v, off, 64);
        lm += __shfl_down(lm, off, 64);
    }
    __shared__ float rv[4], rl[4];
    int wid = threadIdx.x >> 6, lane = threadIdx.x & 63;
    if (lane == 0) { rv[wid] = v; rl[wid] = lm; }
    __syncthreads();
    if (threadIdx.x == 0) {
        atomicAdd(&accum[0], rv[0] + rv[1] + rv[2] + rv[3]);
        atomicAdd(&accum[1], rl[0] + rl[1] + rl[2] + rl[3]);
    }
}

__global__ void writeout_kernel(const float* __restrict__ accum, float* __restrict__ out) {
    out[0] = -accum[0] / (accum[1] + 1e-6f);
}

extern "C" void kernel_launch(void* const* d_in, const int* in_sizes, int n_in,
                              void* d_out, int out_size, void* d_ws, size_t ws_size,
                              hipStream_t stream) {
    const int*   indices    = (const int*)  d_in[0];
    const float* mask       = (const float*)d_in[1];
    const int*   labels     = (const int*)  d_in[2];
    const float* label_mask = (const float*)d_in[3];
    const int*   negs       = (const int*)  d_in[4];
    const float* embed      = (const float*)d_in[5];
    const float* Wk         = (const float*)d_in[6];
    float* out = (float*)d_out;

    // workspace layout (~79 MB)
    float* WsubT      = (float*)d_ws;                           // 512*18432 f32
    float* Wsrt       = WsubT + (size_t)DDIM * NSUB;            // 512*18432 f32
    float* query      = Wsrt  + (size_t)DDIM * NSUB;            // 1024*512 f32
    int*   all_idx    = (int*)(query + (size_t)BDIM * DDIM);    // NSUB
    int*   srt_v      = all_idx + NSUB;                         // NSUB
    int*   rank       = srt_v + NSUB;                           // NSUB
    float* norms      = (float*)(rank + NSUB);                  // NSUB
    float* pos_scores = norms + NSUB;                           // NPOS
    float* Zrow       = pos_scores + NPOS;                      // BDIM
    float* accum      = Zrow + BDIM;                            // 2
    int*   cnt        = (int*)(accum + 2);                      // NLAB
    int*   offs       = cnt + NLAB;                             // NLAB
    int*   bsum       = offs + NLAB;                            // 256
    int*   bofs       = bsum + 256;                             // 256

    init_kernel<<<NLAB / 256, 256, 0, stream>>>(cnt, Zrow, accum);
    count_kernel<<<NSUB / 256, 256, 0, stream>>>(labels, negs, all_idx, cnt);
    query_kernel<<<BDIM, 256, 0, stream>>>(indices, mask, embed, query);
    scan1_kernel<<<NLAB / 512, 256, 0, stream>>>(cnt, offs, bsum);
    scan2_kernel<<<1, 256, 0, stream>>>(bsum, bofs);
    scan3_kernel<<<NLAB / 256, 256, 0, stream>>>(offs, bofs);
    place_kernel<<<NSUB / 256, 256, 0, stream>>>(all_idx, offs, srt_v, rank);
    gather_kernel<<<DDIM, 256, 0, stream>>>(Wk, srt_v, Wsrt);
    permute_kernel<<<DDIM, 256, 0, stream>>>(Wsrt, rank, WsubT);
    norms_kernel<<<NSUB / 256, 256, 0, stream>>>(WsubT, norms);
    pos_kernel<<<NPOS / 256, 256, 0, stream>>>(query, WsubT, norms, pos_scores, Zrow);
    neg_kernel<<<dim3(BDIM / BM, NNEG / BN), 256, 0, stream>>>(query, WsubT, norms, Zrow);
    finalize_kernel<<<NPOS / 256, 256, 0, stream>>>(pos_scores, label_mask, Zrow, accum);
    writeout_kernel<<<1, 1, 0, stream>>>(accum, out);
}

// Round 4
// 152.493 us; speedup vs baseline: 3.2204x; 1.7771x over previous
//
#include <hip/hip_runtime.h>
#include <hip/hip_bf16.h>

#define BDIM 1024
#define LDIM 128
#define KDIM 16
#define DDIM 512
#define NFEAT 100000
#define NLAB 131072
#define NNEG 2048
#define NPOS (BDIM * KDIM)      /* 16384 */
#define NSUB (NPOS + NNEG)      /* 18432 */
#define EPSV 0.1f
#define CV 2.1f

typedef __attribute__((ext_vector_type(8))) short s8v;
typedef __attribute__((ext_vector_type(4))) float f4v;

static __device__ __forceinline__ unsigned short f2bf(float x) {
    union { float f; unsigned u; } v; v.f = x;
    unsigned r = v.u + 0x7FFF + ((v.u >> 16) & 1);   // RNE
    return (unsigned short)(r >> 16);
}
static __device__ __forceinline__ float bf2f(unsigned short h) {
    return __uint_as_float((unsigned)h << 16);
}

// ---------------- init: zero cnt, norms2, Zrow, accum ----------------
__global__ __launch_bounds__(256) void init_kernel(int* __restrict__ cnt,
                                                   float* __restrict__ norms2,
                                                   float* __restrict__ Zrow,
                                                   float* __restrict__ accum) {
    int j = blockIdx.x * 256 + threadIdx.x;   // grid covers NLAB
    cnt[j] = 0;
    if (j < NSUB) norms2[j] = 0.f;
    if (j < BDIM) Zrow[j] = 0.f;
    if (j < 2) accum[j] = 0.f;
}

// ---------------- count: all_idx + histogram ----------------
__global__ __launch_bounds__(256) void count_kernel(const int* __restrict__ labels,
                                                    const int* __restrict__ negs,
                                                    int* __restrict__ all_idx,
                                                    int* __restrict__ cnt) {
    int j = blockIdx.x * 256 + threadIdx.x;
    if (j >= NSUB) return;
    int v = (j < NPOS) ? max(labels[j], 0) : negs[j - NPOS];
    all_idx[j] = v;
    atomicAdd(&cnt[v], 1);
}

// ---------------- scan1: per-block exclusive scan of 512 counts ----------------
__global__ __launch_bounds__(256) void scan1_kernel(const int* __restrict__ cnt,
                                                    int* __restrict__ offs,
                                                    int* __restrict__ bsum) {
    int t = threadIdx.x;
    int base = blockIdx.x * 512;
    int a0 = cnt[base + 2 * t], a1 = cnt[base + 2 * t + 1];
    int chunk = a0 + a1;
    int ts = chunk;
    int lane = t & 63, wid = t >> 6;
    #pragma unroll
    for (int off = 1; off < 64; off <<= 1) {
        int v = __shfl_up(ts, off, 64);
        if (lane >= off) ts += v;
    }
    __shared__ int wsum[4];
    if (lane == 63) wsum[wid] = ts;
    __syncthreads();
    int woff = 0;
    for (int w = 0; w < wid; ++w) woff += wsum[w];
    int incl = woff + ts;
    int excl = incl - chunk;
    offs[base + 2 * t]     = excl;
    offs[base + 2 * t + 1] = excl + a0;
    if (t == 255) bsum[blockIdx.x] = incl;
}

// ---------------- scan2: exclusive scan of 256 block sums ----------------
__global__ __launch_bounds__(256) void scan2_kernel(const int* __restrict__ bsum,
                                                    int* __restrict__ bofs) {
    int t = threadIdx.x;
    int a = bsum[t];
    int ts = a;
    int lane = t & 63, wid = t >> 6;
    #pragma unroll
    for (int off = 1; off < 64; off <<= 1) {
        int v = __shfl_up(ts, off, 64);
        if (lane >= off) ts += v;
    }
    __shared__ int wsum[4];
    if (lane == 63) wsum[wid] = ts;
    __syncthreads();
    int woff = 0;
    for (int w = 0; w < wid; ++w) woff += wsum[w];
    bofs[t] = woff + ts - a;
}

// ---------------- scan3: add block offsets ----------------
__global__ __launch_bounds__(256) void scan3_kernel(int* __restrict__ offs,
                                                    const int* __restrict__ bofs) {
    int v = blockIdx.x * 256 + threadIdx.x;
    offs[v] += bofs[v >> 9];
}

// ---------------- place: sorted order + rank ----------------
__global__ __launch_bounds__(256) void place_kernel(const int* __restrict__ all_idx,
                                                    int* __restrict__ offs,
                                                    int* __restrict__ srt_v,
                                                    int* __restrict__ rank) {
    int j = blockIdx.x * 256 + threadIdx.x;
    if (j >= NSUB) return;
    int v = all_idx[j];
    int r = atomicAdd(&offs[v], 1);
    srt_v[r] = v;
    rank[j] = r;
}

// ---------------- query: embed gather-sum + normalize (f32 + bf16 out) ----------------
__global__ __launch_bounds__(256) void query_kernel(const int* __restrict__ indices,
                                                    const float* __restrict__ mask,
                                                    const float* __restrict__ embed,
                                                    float* __restrict__ query,
                                                    unsigned short* __restrict__ qbf) {
    __shared__ int   sidx[LDIM];
    __shared__ float smask[LDIM];
    int b = blockIdx.x;
    int t = threadIdx.x;
    if (t < LDIM) {
        sidx[t]  = indices[b * LDIM + t];
        smask[t] = mask[b * LDIM + t];
    }
    __syncthreads();

    float ax = 0.f, ay = 0.f, msum = 0.f;
    #pragma unroll 2
    for (int l = 0; l < LDIM; l += 4) {
        int   i0 = sidx[l],     i1 = sidx[l + 1],  i2 = sidx[l + 2],  i3 = sidx[l + 3];
        float m0 = smask[l],    m1 = smask[l + 1], m2 = smask[l + 2], m3 = smask[l + 3];
        float2 r0 = *(const float2*)&embed[(size_t)i0 * DDIM + t * 2];
        float2 r1 = *(const float2*)&embed[(size_t)i1 * DDIM + t * 2];
        float2 r2 = *(const float2*)&embed[(size_t)i2 * DDIM + t * 2];
        float2 r3 = *(const float2*)&embed[(size_t)i3 * DDIM + t * 2];
        msum += m0 + m1 + m2 + m3;
        ax += m0 * r0.x + m1 * r1.x + m2 * r2.x + m3 * r3.x;
        ay += m0 * r0.y + m1 * r1.y + m2 * r2.y + m3 * r3.y;
    }
    float denom = fmaxf(msum, 1.0f);
    ax /= denom; ay /= denom;

    float ss = ax * ax + ay * ay;
    #pragma unroll
    for (int off = 32; off > 0; off >>= 1) ss += __shfl_down(ss, off, 64);
    __shared__ float red[4];
    __shared__ float snorm;
    int wid = t >> 6, lane = t & 63;
    if (lane == 0) red[wid] = ss;
    __syncthreads();
    if (t == 0) snorm = sqrtf(red[0] + red[1] + red[2] + red[3]);
    __syncthreads();
    float inv = 1.f / fmaxf(snorm, 1e-4f);
    float2 o = { ax * inv, ay * inv };
    *(float2*)&query[(size_t)b * DDIM + t * 2] = o;
    ushort2 ob = { f2bf(o.x), f2bf(o.y) };
    *(ushort2*)&qbf[(size_t)b * DDIM + t * 2] = ob;
}

// ---------------- gather: Wsrt[d][r] = bf16(Wk[d][srt_v[r]]) ----------------
__global__ __launch_bounds__(256) void gather_kernel(const float* __restrict__ Wk,
                                                     const int* __restrict__ srt_v,
                                                     unsigned short* __restrict__ Wsrt) {
    int d = blockIdx.x;
    int half = blockIdx.y;
    const float* row = Wk + (size_t)d * NLAB;
    unsigned short* o = Wsrt + (size_t)d * NSUB;
    int r0 = half * (NSUB / 2), r1 = r0 + NSUB / 2;
    #pragma unroll 4
    for (int r = r0 + threadIdx.x; r < r1; r += 256) {
        int v = srt_v[r];
        o[r] = f2bf(__builtin_nontemporal_load(&row[v]));
    }
}

// ---------------- transpose: WT[r][k] = Wsrt[k][r], fused column sumsq ----------------
__global__ __launch_bounds__(256) void transpose_kernel(const unsigned short* __restrict__ Wsrt,
                                                        unsigned short* __restrict__ WT,
                                                        float* __restrict__ norms2) {
    __shared__ unsigned short tile[64][66];   // word stride 33 -> conflict-free
    __shared__ float psum[64];
    int t = threadIdx.x;
    int r0 = blockIdx.x * 64;
    int d0 = blockIdx.y * 64;
    if (t < 64) psum[t] = 0.f;
    __syncthreads();
    float local = 0.f;
    int rl = t & 63;
    #pragma unroll 4
    for (int it = 0; it < 16; ++it) {
        int dl = it * 4 + (t >> 6);
        unsigned short v = Wsrt[(size_t)(d0 + dl) * NSUB + r0 + rl];
        tile[rl][dl] = v;
        float f = bf2f(v);
        local += f * f;
    }
    atomicAdd(&psum[rl], local);
    __syncthreads();
    #pragma unroll 4
    for (int it = 0; it < 16; ++it) {
        int rr = it * 4 + (t >> 6);
        WT[(size_t)(r0 + rr) * DDIM + d0 + rl] = tile[rr][rl];
    }
    if (t < 64) atomicAdd(&norms2[r0 + t], psum[t]);
}

// ---------------- positive scores: wave handles 16 j (one b) ----------------
__global__ __launch_bounds__(256) void pos_kernel(const float* __restrict__ query,
                                                  const unsigned short* __restrict__ WT,
                                                  const int* __restrict__ rank,
                                                  const float* __restrict__ norms2,
                                                  float* __restrict__ pos_scores,
                                                  float* __restrict__ Zrow) {
    int t = threadIdx.x;
    int w = t >> 6, l = t & 63;
    int b = blockIdx.x * 4 + w;              // j-group == b
    int j = b * KDIM + (l & 15);
    int r = rank[j];
    int g = l >> 4;                          // k-chunk
    const unsigned short* wrow = WT + (size_t)r * DDIM + g * 128;
    const float* qrow = query + (size_t)b * DDIM + g * 128;
    float acc = 0.f;
    #pragma unroll
    for (int kk = 0; kk < 128; kk += 8) {
        ushort4 w0 = *(const ushort4*)&wrow[kk];
        ushort4 w1 = *(const ushort4*)&wrow[kk + 4];
        float4 q0 = *(const float4*)&qrow[kk];
        float4 q1 = *(const float4*)&qrow[kk + 4];
        acc += bf2f(w0.x) * q0.x + bf2f(w0.y) * q0.y + bf2f(w0.z) * q0.z + bf2f(w0.w) * q0.w
             + bf2f(w1.x) * q1.x + bf2f(w1.y) * q1.y + bf2f(w1.z) * q1.z + bf2f(w1.w) * q1.w;
    }
    acc += __shfl_xor(acc, 16, 64);
    acc += __shfl_xor(acc, 32, 64);
    if (l < 16) {
        float nrm = fmaxf(sqrtf(norms2[r]), 1e-4f);
        float dot = fminf(fmaxf(acc / nrm, -0.999f), 0.999f);
        float sc = dot * dot / fmaxf(CV - 2.f * dot, EPSV);
        pos_scores[j] = sc;
        float s = sc;
        s += __shfl_xor(s, 1, 64); s += __shfl_xor(s, 2, 64);
        s += __shfl_xor(s, 4, 64); s += __shfl_xor(s, 8, 64);
        if (l == 0) atomicAdd(&Zrow[b], s);
    }
}

// ---------------- negative GEMM via MFMA bf16, fused score + Z row-sum ----------------
static __device__ __forceinline__ float score_of(float acc, float nn) {
    float dot = acc / nn;
    dot = fminf(fmaxf(dot, -0.999f), 0.999f);
    return dot * dot / fmaxf(CV - 2.f * dot, EPSV);
}

__global__ __launch_bounds__(256) void neg_kernel(const unsigned short* __restrict__ qbf,
                                                  const unsigned short* __restrict__ WT,
                                                  const int* __restrict__ rank,
                                                  const float* __restrict__ norms2,
                                                  float* __restrict__ Zrow) {
    __shared__ float rowsum[64];
    int t = threadIdx.x;
    int w = t >> 6, l = t & 63;
    int wm = w >> 1, wn = w & 1;
    int lr = l & 15, lg = l >> 4;
    int m0 = blockIdx.x * 64 + wm * 32;      // query rows for this wave
    int n0 = blockIdx.y * 64 + wn * 32;      // neg cols for this wave
    if (t < 64) rowsum[t] = 0.f;
    __syncthreads();

    int rB0 = rank[NPOS + n0 + lr];
    int rB1 = rank[NPOS + n0 + 16 + lr];
    const unsigned short* a0p = qbf + (size_t)(m0 + lr) * DDIM + lg * 8;
    const unsigned short* a1p = qbf + (size_t)(m0 + 16 + lr) * DDIM + lg * 8;
    const unsigned short* b0p = WT + (size_t)rB0 * DDIM + lg * 8;
    const unsigned short* b1p = WT + (size_t)rB1 * DDIM + lg * 8;

    f4v acc00 = {0.f, 0.f, 0.f, 0.f}, acc01 = acc00, acc10 = acc00, acc11 = acc00;
    #pragma unroll
    for (int k0 = 0; k0 < DDIM; k0 += 32) {
        s8v a0 = *(const s8v*)(a0p + k0);
        s8v a1 = *(const s8v*)(a1p + k0);
        s8v b0 = *(const s8v*)(b0p + k0);
        s8v b1 = *(const s8v*)(b1p + k0);
        acc00 = __builtin_amdgcn_mfma_f32_16x16x32_bf16(a0, b0, acc00, 0, 0, 0);
        acc01 = __builtin_amdgcn_mfma_f32_16x16x32_bf16(a0, b1, acc01, 0, 0, 0);
        acc10 = __builtin_amdgcn_mfma_f32_16x16x32_bf16(a1, b0, acc10, 0, 0, 0);
        acc11 = __builtin_amdgcn_mfma_f32_16x16x32_bf16(a1, b1, acc11, 0, 0, 0);
    }

    // D layout: col = n_base + (l&15), row = m_base + lg*4 + i
    float nn0 = fmaxf(sqrtf(norms2[rB0]), 1e-4f);
    float nn1 = fmaxf(sqrtf(norms2[rB1]), 1e-4f);
    float s[8];
    #pragma unroll
    for (int i = 0; i < 4; ++i) {
        s[i]     = score_of(acc00[i], nn0) + score_of(acc01[i], nn1);  // rows m0+lg*4+i
        s[4 + i] = score_of(acc10[i], nn0) + score_of(acc11[i], nn1);  // rows m0+16+lg*4+i
    }
    #pragma unroll
    for (int i = 0; i < 8; ++i) {
        s[i] += __shfl_xor(s[i], 1, 64);
        s[i] += __shfl_xor(s[i], 2, 64);
        s[i] += __shfl_xor(s[i], 4, 64);
        s[i] += __shfl_xor(s[i], 8, 64);
    }
    if (lr == 0) {
        #pragma unroll
        for (int i = 0; i < 4; ++i) {
            atomicAdd(&rowsum[wm * 32 + lg * 4 + i], s[i]);
            atomicAdd(&rowsum[wm * 32 + 16 + lg * 4 + i], s[4 + i]);
        }
    }
    __syncthreads();
    if (t < 64) atomicAdd(&Zrow[blockIdx.x * 64 + t], rowsum[t]);
}

// ---------------- finalize ----------------
__global__ __launch_bounds__(256) void finalize_kernel(const float* __restrict__ pos_scores,
                                                       const float* __restrict__ label_mask,
                                                       const float* __restrict__ Zrow,
                                                       float* __restrict__ accum) {
    int j = blockIdx.x * 256 + threadIdx.x;
    int b = j >> 4;
    float lm = label_mask[j];
    float logZ = logf(Zrow[b] + (float)(KDIM + NNEG) * 1e-8f);
    float v = lm * (logf(pos_scores[j] + 1e-8f) - logZ);
    #pragma unroll
    for (int off = 32; off > 0; off >>= 1) {
        v  += __shfl_down(v, off, 64);
        lm += __shfl_down(lm, off, 64);
    }
    __shared__ float rv[4], rl[4];
    int wid = threadIdx.x >> 6, lane = threadIdx.x & 63;
    if (lane == 0) { rv[wid] = v; rl[wid] = lm; }
    __syncthreads();
    if (threadIdx.x == 0) {
        atomicAdd(&accum[0], rv[0] + rv[1] + rv[2] + rv[3]);
        atomicAdd(&accum[1], rl[0] + rl[1] + rl[2] + rl[3]);
    }
}

__global__ void writeout_kernel(const float* __restrict__ accum, float* __restrict__ out) {
    out[0] = -accum[0] / (accum[1] + 1e-6f);
}

extern "C" void kernel_launch(void* const* d_in, const int* in_sizes, int n_in,
                              void* d_out, int out_size, void* d_ws, size_t ws_size,
                              hipStream_t stream) {
    const int*   indices    = (const int*)  d_in[0];
    const float* mask       = (const float*)d_in[1];
    const int*   labels     = (const int*)  d_in[2];
    const float* label_mask = (const float*)d_in[3];
    const int*   negs       = (const int*)  d_in[4];
    const float* embed      = (const float*)d_in[5];
    const float* Wk         = (const float*)d_in[6];
    float* out = (float*)d_out;

    // workspace layout (~45 MB)
    unsigned short* Wsrt = (unsigned short*)d_ws;                   // 512*18432 bf16
    unsigned short* WT   = Wsrt + (size_t)DDIM * NSUB;              // 18432*512 bf16
    float* query      = (float*)(WT + (size_t)NSUB * DDIM);         // 1024*512 f32
    unsigned short* qbf = (unsigned short*)(query + (size_t)BDIM * DDIM); // 1024*512 bf16
    int*   all_idx    = (int*)(qbf + (size_t)BDIM * DDIM);          // NSUB
    int*   srt_v      = all_idx + NSUB;                             // NSUB
    int*   rank       = srt_v + NSUB;                               // NSUB
    float* norms2     = (float*)(rank + NSUB);                      // NSUB
    float* pos_scores = norms2 + NSUB;                              // NPOS
    float* Zrow       = pos_scores + NPOS;                          // BDIM
    float* accum      = Zrow + BDIM;                                // 2
    int*   cnt        = (int*)(accum + 2);                          // NLAB
    int*   offs       = cnt + NLAB;                                 // NLAB
    int*   bsum       = offs + NLAB;                                // 256
    int*   bofs       = bsum + 256;                                 // 256

    init_kernel<<<NLAB / 256, 256, 0, stream>>>(cnt, norms2, Zrow, accum);
    count_kernel<<<NSUB / 256, 256, 0, stream>>>(labels, negs, all_idx, cnt);
    query_kernel<<<BDIM, 256, 0, stream>>>(indices, mask, embed, query, qbf);
    scan1_kernel<<<NLAB / 512, 256, 0, stream>>>(cnt, offs, bsum);
    scan2_kernel<<<1, 256, 0, stream>>>(bsum, bofs);
    scan3_kernel<<<NLAB / 256, 256, 0, stream>>>(offs, bofs);
    place_kernel<<<NSUB / 256, 256, 0, stream>>>(all_idx, offs, srt_v, rank);
    gather_kernel<<<dim3(DDIM, 2), 256, 0, stream>>>(Wk, srt_v, Wsrt);
    transpose_kernel<<<dim3(NSUB / 64, DDIM / 64), 256, 0, stream>>>(Wsrt, WT, norms2);
    pos_kernel<<<NPOS / 64, 256, 0, stream>>>(query, WT, rank, norms2, pos_scores, Zrow);
    neg_kernel<<<dim3(BDIM / 64, NNEG / 64), 256, 0, stream>>>(qbf, WT, rank, norms2, Zrow);
    finalize_kernel<<<NPOS / 256, 256, 0, stream>>>(pos_scores, label_mask, Zrow, accum);
    writeout_kernel<<<1, 1, 0, stream>>>(accum, out);
}

// Round 5
// 152.123 us; speedup vs baseline: 3.2282x; 1.0024x over previous
//
#include <hip/hip_runtime.h>
#include <hip/hip_bf16.h>

#define BDIM 1024
#define LDIM 128
#define KDIM 16
#define DDIM 512
#define NLAB 131072
#define NNEG 2048
#define NPOS (BDIM * KDIM)      /* 16384 */
#define NSUB (NPOS + NNEG)      /* 18432 */
#define EPSV 0.1f
#define CV 2.1f
#define NBUCK 512               /* labels per bucket = 256 -> shift 8 */
#define GT_BLOCKS ((NSUB / 64) * (DDIM / 64))   /* 288*8 = 2304 */

typedef __attribute__((ext_vector_type(8))) short s8v;
typedef __attribute__((ext_vector_type(4))) float f4v;

static __device__ __forceinline__ unsigned short f2bf(float x) {
    union { float f; unsigned u; } v; v.f = x;
    unsigned r = v.u + 0x7FFF + ((v.u >> 16) & 1);   // RNE
    return (unsigned short)(r >> 16);
}
static __device__ __forceinline__ float bf2f(unsigned short h) {
    return __uint_as_float((unsigned)h << 16);
}

// ---------------- init: zero cnt/norms2/Zrow/accum/ticket ----------------
__global__ __launch_bounds__(256) void init_kernel(int* __restrict__ cnt,
                                                   float* __restrict__ norms2,
                                                   float* __restrict__ Zrow,
                                                   float* __restrict__ accum,
                                                   int* __restrict__ ticket) {
    int j = blockIdx.x * 256 + threadIdx.x;   // grid covers NSUB
    if (j < NSUB) norms2[j] = 0.f;
    if (j < NBUCK) cnt[j] = 0;
    if (j < BDIM) Zrow[j] = 0.f;
    if (j < 2) accum[j] = 0.f;
    if (j == 0) *ticket = 0;
}

// ---------------- count: all_idx + 512-bucket histogram ----------------
__global__ __launch_bounds__(256) void count_kernel(const int* __restrict__ labels,
                                                    const int* __restrict__ negs,
                                                    int* __restrict__ all_idx,
                                                    int* __restrict__ cnt) {
    int j = blockIdx.x * 256 + threadIdx.x;
    if (j >= NSUB) return;
    int v = (j < NPOS) ? max(labels[j], 0) : negs[j - NPOS];
    all_idx[j] = v;
    atomicAdd(&cnt[v >> 8], 1);
}

// ---------------- scan: single-block exclusive scan of 512 buckets ----------------
__global__ __launch_bounds__(256) void scan_kernel(const int* __restrict__ cnt,
                                                   int* __restrict__ offs) {
    int t = threadIdx.x;
    int a0 = cnt[2 * t], a1 = cnt[2 * t + 1];
    int chunk = a0 + a1;
    int ts = chunk;
    int lane = t & 63, wid = t >> 6;
    #pragma unroll
    for (int off = 1; off < 64; off <<= 1) {
        int v = __shfl_up(ts, off, 64);
        if (lane >= off) ts += v;
    }
    __shared__ int wsum[4];
    if (lane == 63) wsum[wid] = ts;
    __syncthreads();
    int woff = 0;
    for (int w = 0; w < wid; ++w) woff += wsum[w];
    int incl = woff + ts;
    int excl = incl - chunk;
    offs[2 * t]     = excl;
    offs[2 * t + 1] = excl + a0;
}

// ---------------- place: bucket-sorted slot + rank ----------------
__global__ __launch_bounds__(256) void place_kernel(const int* __restrict__ all_idx,
                                                    int* __restrict__ offs,
                                                    int* __restrict__ srt_v,
                                                    int* __restrict__ rank) {
    int j = blockIdx.x * 256 + threadIdx.x;
    if (j >= NSUB) return;
    int v = all_idx[j];
    int r = atomicAdd(&offs[v >> 8], 1);
    srt_v[r] = v;
    rank[j] = r;
}

// ---------------- main1: fused [gather+transpose+norms] and [query] ----------------
__global__ __launch_bounds__(256) void main1_kernel(const float* __restrict__ Wk,
                                                    const int* __restrict__ srt_v,
                                                    unsigned short* __restrict__ WT,
                                                    float* __restrict__ norms2,
                                                    const int* __restrict__ indices,
                                                    const float* __restrict__ mask,
                                                    const float* __restrict__ embed,
                                                    float* __restrict__ query,
                                                    unsigned short* __restrict__ qbf) {
    int t = threadIdx.x;
    if (blockIdx.x < GT_BLOCKS) {
        // ---- gather + transpose: 64 r  x 64 d tile ----
        __shared__ unsigned short tile[64][66];
        __shared__ float psum[64];
        int bt = blockIdx.x;
        int rt = bt % (NSUB / 64);     // 288
        int dt = bt / (NSUB / 64);     // 8
        int r0 = rt * 64, d0 = dt * 64;
        int l = t & 63, w = t >> 6;
        if (t < 64) psum[t] = 0.f;
        __syncthreads();
        int v = srt_v[r0 + l];
        float local = 0.f;
        #pragma unroll
        for (int i = 0; i < 16; ++i) {
            int dl = w * 16 + i;
            float f = __builtin_nontemporal_load(&Wk[(size_t)(d0 + dl) * NLAB + v]);
            unsigned short h = f2bf(f);
            tile[l][dl] = h;
            float bf = bf2f(h);
            local += bf * bf;
        }
        atomicAdd(&psum[l], local);
        __syncthreads();
        #pragma unroll
        for (int i = 0; i < 16; ++i) {
            int rr = w * 16 + i;
            WT[(size_t)(r0 + rr) * DDIM + d0 + l] = tile[rr][l];
        }
        if (t < 64) atomicAdd(&norms2[r0 + t], psum[t]);
    } else {
        // ---- query: embed gather-sum + normalize ----
        __shared__ int   sidx[LDIM];
        __shared__ float smask[LDIM];
        __shared__ float red[4];
        __shared__ float snorm;
        int b = blockIdx.x - GT_BLOCKS;
        if (t < LDIM) {
            sidx[t]  = indices[b * LDIM + t];
            smask[t] = mask[b * LDIM + t];
        }
        __syncthreads();
        float ax = 0.f, ay = 0.f, msum = 0.f;
        #pragma unroll 2
        for (int l = 0; l < LDIM; l += 4) {
            int   i0 = sidx[l],   i1 = sidx[l + 1],  i2 = sidx[l + 2],  i3 = sidx[l + 3];
            float m0 = smask[l],  m1 = smask[l + 1], m2 = smask[l + 2], m3 = smask[l + 3];
            float2 r0 = *(const float2*)&embed[(size_t)i0 * DDIM + t * 2];
            float2 r1 = *(const float2*)&embed[(size_t)i1 * DDIM + t * 2];
            float2 r2 = *(const float2*)&embed[(size_t)i2 * DDIM + t * 2];
            float2 r3 = *(const float2*)&embed[(size_t)i3 * DDIM + t * 2];
            msum += m0 + m1 + m2 + m3;
            ax += m0 * r0.x + m1 * r1.x + m2 * r2.x + m3 * r3.x;
            ay += m0 * r0.y + m1 * r1.y + m2 * r2.y + m3 * r3.y;
        }
        float denom = fmaxf(msum, 1.0f);
        ax /= denom; ay /= denom;
        float ss = ax * ax + ay * ay;
        #pragma unroll
        for (int off = 32; off > 0; off >>= 1) ss += __shfl_down(ss, off, 64);
        int wid = t >> 6, lane = t & 63;
        if (lane == 0) red[wid] = ss;
        __syncthreads();
        if (t == 0) snorm = sqrtf(red[0] + red[1] + red[2] + red[3]);
        __syncthreads();
        float inv = 1.f / fmaxf(snorm, 1e-4f);
        float2 o = { ax * inv, ay * inv };
        *(float2*)&query[(size_t)b * DDIM + t * 2] = o;
        ushort2 ob = { f2bf(o.x), f2bf(o.y) };
        *(ushort2*)&qbf[(size_t)b * DDIM + t * 2] = ob;
    }
}

// ---------------- main2: fused [neg MFMA GEMM] and [pos dots] ----------------
static __device__ __forceinline__ float score_of(float acc, float nn) {
    float dot = acc / nn;
    dot = fminf(fmaxf(dot, -0.999f), 0.999f);
    return dot * dot / fmaxf(CV - 2.f * dot, EPSV);
}

__global__ __launch_bounds__(256) void main2_kernel(const unsigned short* __restrict__ qbf,
                                                    const float* __restrict__ query,
                                                    const unsigned short* __restrict__ WT,
                                                    const int* __restrict__ rank,
                                                    const float* __restrict__ norms2,
                                                    float* __restrict__ pos_scores,
                                                    float* __restrict__ Zrow) {
    int t = threadIdx.x;
    int w = t >> 6, l = t & 63;
    if (blockIdx.x < (BDIM / 64) * (NNEG / 64)) {
        // ---- negatives: 64x64 tile via MFMA ----
        __shared__ float rowsum[64];
        int bx = blockIdx.x;
        int mt = bx & 15, nt = bx >> 4;
        int wm = w >> 1, wn = w & 1;
        int lr = l & 15, lg = l >> 4;
        int m0 = mt * 64 + wm * 32;
        int n0 = nt * 64 + wn * 32;
        if (t < 64) rowsum[t] = 0.f;
        __syncthreads();

        int rB0 = rank[NPOS + n0 + lr];
        int rB1 = rank[NPOS + n0 + 16 + lr];
        const unsigned short* a0p = qbf + (size_t)(m0 + lr) * DDIM + lg * 8;
        const unsigned short* a1p = qbf + (size_t)(m0 + 16 + lr) * DDIM + lg * 8;
        const unsigned short* b0p = WT + (size_t)rB0 * DDIM + lg * 8;
        const unsigned short* b1p = WT + (size_t)rB1 * DDIM + lg * 8;

        f4v acc00 = {0.f, 0.f, 0.f, 0.f}, acc01 = acc00, acc10 = acc00, acc11 = acc00;
        #pragma unroll
        for (int k0 = 0; k0 < DDIM; k0 += 32) {
            s8v a0 = *(const s8v*)(a0p + k0);
            s8v a1 = *(const s8v*)(a1p + k0);
            s8v b0 = *(const s8v*)(b0p + k0);
            s8v b1 = *(const s8v*)(b1p + k0);
            acc00 = __builtin_amdgcn_mfma_f32_16x16x32_bf16(a0, b0, acc00, 0, 0, 0);
            acc01 = __builtin_amdgcn_mfma_f32_16x16x32_bf16(a0, b1, acc01, 0, 0, 0);
            acc10 = __builtin_amdgcn_mfma_f32_16x16x32_bf16(a1, b0, acc10, 0, 0, 0);
            acc11 = __builtin_amdgcn_mfma_f32_16x16x32_bf16(a1, b1, acc11, 0, 0, 0);
        }

        float nn0 = fmaxf(sqrtf(norms2[rB0]), 1e-4f);
        float nn1 = fmaxf(sqrtf(norms2[rB1]), 1e-4f);
        float s[8];
        #pragma unroll
        for (int i = 0; i < 4; ++i) {
            s[i]     = score_of(acc00[i], nn0) + score_of(acc01[i], nn1);
            s[4 + i] = score_of(acc10[i], nn0) + score_of(acc11[i], nn1);
        }
        #pragma unroll
        for (int i = 0; i < 8; ++i) {
            s[i] += __shfl_xor(s[i], 1, 64);
            s[i] += __shfl_xor(s[i], 2, 64);
            s[i] += __shfl_xor(s[i], 4, 64);
            s[i] += __shfl_xor(s[i], 8, 64);
        }
        if (lr == 0) {
            #pragma unroll
            for (int i = 0; i < 4; ++i) {
                atomicAdd(&rowsum[wm * 32 + lg * 4 + i], s[i]);
                atomicAdd(&rowsum[wm * 32 + 16 + lg * 4 + i], s[4 + i]);
            }
        }
        __syncthreads();
        if (t < 64) atomicAdd(&Zrow[mt * 64 + t], rowsum[t]);
    } else {
        // ---- positives: wave handles one b (16 j) ----
        int px = blockIdx.x - (BDIM / 64) * (NNEG / 64);
        int b = px * 4 + w;
        int j = b * KDIM + (l & 15);
        int r = rank[j];
        int g = l >> 4;
        const unsigned short* wrow = WT + (size_t)r * DDIM + g * 128;
        const float* qrow = query + (size_t)b * DDIM + g * 128;
        float acc = 0.f;
        #pragma unroll
        for (int kk = 0; kk < 128; kk += 8) {
            ushort4 w0 = *(const ushort4*)&wrow[kk];
            ushort4 w1 = *(const ushort4*)&wrow[kk + 4];
            float4 q0 = *(const float4*)&qrow[kk];
            float4 q1 = *(const float4*)&qrow[kk + 4];
            acc += bf2f(w0.x) * q0.x + bf2f(w0.y) * q0.y + bf2f(w0.z) * q0.z + bf2f(w0.w) * q0.w
                 + bf2f(w1.x) * q1.x + bf2f(w1.y) * q1.y + bf2f(w1.z) * q1.z + bf2f(w1.w) * q1.w;
        }
        acc += __shfl_xor(acc, 16, 64);
        acc += __shfl_xor(acc, 32, 64);
        if (l < 16) {
            float nrm = fmaxf(sqrtf(norms2[r]), 1e-4f);
            float dot = fminf(fmaxf(acc / nrm, -0.999f), 0.999f);
            float sc = dot * dot / fmaxf(CV - 2.f * dot, EPSV);
            pos_scores[j] = sc;
            float s = sc;
            s += __shfl_xor(s, 1, 64); s += __shfl_xor(s, 2, 64);
            s += __shfl_xor(s, 4, 64); s += __shfl_xor(s, 8, 64);
            if (l == 0) atomicAdd(&Zrow[b], s);
        }
    }
}

// ---------------- finalize (+writeout via ticket) ----------------
__global__ __launch_bounds__(256) void finalize_kernel(const float* __restrict__ pos_scores,
                                                       const float* __restrict__ label_mask,
                                                       const float* __restrict__ Zrow,
                                                       float* __restrict__ accum,
                                                       int* __restrict__ ticket,
                                                       float* __restrict__ out) {
    int j = blockIdx.x * 256 + threadIdx.x;
    int b = j >> 4;
    float lm = label_mask[j];
    float logZ = logf(Zrow[b] + (float)(KDIM + NNEG) * 1e-8f);
    float v = lm * (logf(pos_scores[j] + 1e-8f) - logZ);
    #pragma unroll
    for (int off = 32; off > 0; off >>= 1) {
        v  += __shfl_down(v, off, 64);
        lm += __shfl_down(lm, off, 64);
    }
    __shared__ float rv[4], rl[4];
    int wid = threadIdx.x >> 6, lane = threadIdx.x & 63;
    if (lane == 0) { rv[wid] = v; rl[wid] = lm; }
    __syncthreads();
    if (threadIdx.x == 0) {
        atomicAdd(&accum[0], rv[0] + rv[1] + rv[2] + rv[3]);
        atomicAdd(&accum[1], rl[0] + rl[1] + rl[2] + rl[3]);
        __threadfence();
        int old = atomicAdd(ticket, 1);
        if (old == (int)gridDim.x - 1) {
            float a = atomicAdd(&accum[0], 0.f);   // atomic read (current value)
            float m = atomicAdd(&accum[1], 0.f);
            out[0] = -a / (m + 1e-6f);
        }
    }
}

extern "C" void kernel_launch(void* const* d_in, const int* in_sizes, int n_in,
                              void* d_out, int out_size, void* d_ws, size_t ws_size,
                              hipStream_t stream) {
    const int*   indices    = (const int*)  d_in[0];
    const float* mask       = (const float*)d_in[1];
    const int*   labels     = (const int*)  d_in[2];
    const float* label_mask = (const float*)d_in[3];
    const int*   negs       = (const int*)  d_in[4];
    const float* embed      = (const float*)d_in[5];
    const float* Wk         = (const float*)d_in[6];
    float* out = (float*)d_out;

    // workspace layout (~25 MB)
    unsigned short* WT  = (unsigned short*)d_ws;                    // NSUB*DDIM bf16
    float* query      = (float*)(WT + (size_t)NSUB * DDIM);         // BDIM*DDIM f32
    unsigned short* qbf = (unsigned short*)(query + (size_t)BDIM * DDIM); // BDIM*DDIM bf16
    int*   all_idx    = (int*)(qbf + (size_t)BDIM * DDIM);          // NSUB
    int*   srt_v      = all_idx + NSUB;                             // NSUB
    int*   rank       = srt_v + NSUB;                               // NSUB
    float* norms2     = (float*)(rank + NSUB);                      // NSUB
    float* pos_scores = norms2 + NSUB;                              // NPOS
    float* Zrow       = pos_scores + NPOS;                          // BDIM
    float* accum      = Zrow + BDIM;                                // 2
    int*   ticket     = (int*)(accum + 2);                          // 1
    int*   cnt        = ticket + 1;                                 // NBUCK
    int*   offs       = cnt + NBUCK;                                // NBUCK

    init_kernel<<<NSUB / 256, 256, 0, stream>>>(cnt, norms2, Zrow, accum, ticket);
    count_kernel<<<NSUB / 256, 256, 0, stream>>>(labels, negs, all_idx, cnt);
    scan_kernel<<<1, 256, 0, stream>>>(cnt, offs);
    place_kernel<<<NSUB / 256, 256, 0, stream>>>(all_idx, offs, srt_v, rank);
    main1_kernel<<<GT_BLOCKS + BDIM, 256, 0, stream>>>(Wk, srt_v, WT, norms2,
                                                       indices, mask, embed, query, qbf);
    main2_kernel<<<(BDIM / 64) * (NNEG / 64) + NPOS / 64, 256, 0, stream>>>(
        qbf, query, WT, rank, norms2, pos_scores, Zrow);
    finalize_kernel<<<NPOS / 256, 256, 0, stream>>>(pos_scores, label_mask, Zrow,
                                                    accum, ticket, out);
}

// Round 6
// 148.672 us; speedup vs baseline: 3.3032x; 1.0232x over previous
//
#include <hip/hip_runtime.h>
#include <hip/hip_bf16.h>

#define BDIM 1024
#define LDIM 128
#define KDIM 16
#define DDIM 512
#define NLAB 131072
#define NNEG 2048
#define NPOS (BDIM * KDIM)      /* 16384 */
#define NSUB (NPOS + NNEG)      /* 18432 */
#define EPSV 0.1f
#define CV 2.1f
#define NBUCK 512               /* labels per bucket = 256 -> shift 8 */
#define GT_BLOCKS (NBUCK * 8)   /* 512 buckets x 8 d-tiles = 4096 */

typedef __attribute__((ext_vector_type(8))) short s8v;
typedef __attribute__((ext_vector_type(4))) float f4v;
typedef __attribute__((ext_vector_type(4))) float fv4;

static __device__ __forceinline__ unsigned short f2bf(float x) {
    union { float f; unsigned u; } v; v.f = x;
    unsigned r = v.u + 0x7FFF + ((v.u >> 16) & 1);   // RNE
    return (unsigned short)(r >> 16);
}
static __device__ __forceinline__ float bf2f(unsigned short h) {
    return __uint_as_float((unsigned)h << 16);
}

// ---------------- init: zero cnt/norms2/Zrow/accum/ticket ----------------
__global__ __launch_bounds__(256) void init_kernel(int* __restrict__ cnt,
                                                   float* __restrict__ norms2,
                                                   float* __restrict__ Zrow,
                                                   float* __restrict__ accum,
                                                   int* __restrict__ ticket) {
    int j = blockIdx.x * 256 + threadIdx.x;   // grid covers NSUB
    if (j < NSUB) norms2[j] = 0.f;
    if (j < NBUCK) cnt[j] = 0;
    if (j < BDIM) Zrow[j] = 0.f;
    if (j < 2) accum[j] = 0.f;
    if (j == 0) *ticket = 0;
}

// ---------------- count: all_idx + 512-bucket histogram ----------------
__global__ __launch_bounds__(256) void count_kernel(const int* __restrict__ labels,
                                                    const int* __restrict__ negs,
                                                    int* __restrict__ all_idx,
                                                    int* __restrict__ cnt) {
    int j = blockIdx.x * 256 + threadIdx.x;
    if (j >= NSUB) return;
    int v = (j < NPOS) ? max(labels[j], 0) : negs[j - NPOS];
    all_idx[j] = v;
    atomicAdd(&cnt[v >> 8], 1);
}

// ---------------- scan: single-block exclusive scan of 512 buckets ----------------
__global__ __launch_bounds__(256) void scan_kernel(const int* __restrict__ cnt,
                                                   int* __restrict__ offs) {
    int t = threadIdx.x;
    int a0 = cnt[2 * t], a1 = cnt[2 * t + 1];
    int chunk = a0 + a1;
    int ts = chunk;
    int lane = t & 63, wid = t >> 6;
    #pragma unroll
    for (int off = 1; off < 64; off <<= 1) {
        int v = __shfl_up(ts, off, 64);
        if (lane >= off) ts += v;
    }
    __shared__ int wsum[4];
    if (lane == 63) wsum[wid] = ts;
    __syncthreads();
    int woff = 0;
    for (int w = 0; w < wid; ++w) woff += wsum[w];
    int incl = woff + ts;
    int excl = incl - chunk;
    offs[2 * t]     = excl;
    offs[2 * t + 1] = excl + a0;
}

// ---------------- place: bucket-sorted slot + rank ----------------
__global__ __launch_bounds__(256) void place_kernel(const int* __restrict__ all_idx,
                                                    int* __restrict__ offs,
                                                    int* __restrict__ srt_v,
                                                    int* __restrict__ rank) {
    int j = blockIdx.x * 256 + threadIdx.x;
    if (j >= NSUB) return;
    int v = all_idx[j];
    int r = atomicAdd(&offs[v >> 8], 1);   // offs[g] becomes bucket END after this kernel
    srt_v[r] = v;
    rank[j] = r;
}

// ---------------- main1: fused [query] and [W bucket-stream compaction] ----------------
__global__ __launch_bounds__(256) void main1_kernel(const float* __restrict__ Wk,
                                                    const int* __restrict__ srt_v,
                                                    const int* __restrict__ offs_end,
                                                    const int* __restrict__ cnt,
                                                    unsigned short* __restrict__ WT,
                                                    float* __restrict__ norms2,
                                                    const int* __restrict__ indices,
                                                    const float* __restrict__ mask,
                                                    const float* __restrict__ embed,
                                                    float* __restrict__ query,
                                                    unsigned short* __restrict__ qbf) {
    __shared__ __align__(16) unsigned short tile[256][65];   // 33 KB, aliased by query path
    int t = threadIdx.x;
    int w = t >> 6, l = t & 63;

    if (blockIdx.x < BDIM) {
        // ---- query: embed gather-sum + normalize (runs first: latency-bound) ----
        int*   sidx  = (int*)&tile[0][0];
        float* smask = (float*)&tile[16][0];
        float* red   = (float*)&tile[32][0];
        float* snorm = (float*)&tile[33][0];
        int b = blockIdx.x;
        if (t < LDIM) {
            sidx[t]  = indices[b * LDIM + t];
            smask[t] = mask[b * LDIM + t];
        }
        __syncthreads();
        float ax = 0.f, ay = 0.f, msum = 0.f;
        #pragma unroll 2
        for (int ll = 0; ll < LDIM; ll += 4) {
            int   i0 = sidx[ll],   i1 = sidx[ll + 1],  i2 = sidx[ll + 2],  i3 = sidx[ll + 3];
            float m0 = smask[ll],  m1 = smask[ll + 1], m2 = smask[ll + 2], m3 = smask[ll + 3];
            float2 r0 = *(const float2*)&embed[(size_t)i0 * DDIM + t * 2];
            float2 r1 = *(const float2*)&embed[(size_t)i1 * DDIM + t * 2];
            float2 r2 = *(const float2*)&embed[(size_t)i2 * DDIM + t * 2];
            float2 r3 = *(const float2*)&embed[(size_t)i3 * DDIM + t * 2];
            msum += m0 + m1 + m2 + m3;
            ax += m0 * r0.x + m1 * r1.x + m2 * r2.x + m3 * r3.x;
            ay += m0 * r0.y + m1 * r1.y + m2 * r2.y + m3 * r3.y;
        }
        float denom = fmaxf(msum, 1.0f);
        ax /= denom; ay /= denom;
        float ss = ax * ax + ay * ay;
        #pragma unroll
        for (int off = 32; off > 0; off >>= 1) ss += __shfl_down(ss, off, 64);
        if (l == 0) red[w] = ss;
        __syncthreads();
        if (t == 0) snorm[0] = sqrtf(red[0] + red[1] + red[2] + red[3]);
        __syncthreads();
        float inv = 1.f / fmaxf(snorm[0], 1e-4f);
        float2 o = { ax * inv, ay * inv };
        *(float2*)&query[(size_t)b * DDIM + t * 2] = o;
        ushort2 ob = { f2bf(o.x), f2bf(o.y) };
        *(ushort2*)&qbf[(size_t)b * DDIM + t * 2] = ob;
    } else {
        // ---- W bucket-stream: block = (bucket g, 64-d tile) ----
        int bt = blockIdx.x - BDIM;
        int g  = bt >> 3;          // 0..511
        int dt = bt & 7;           // 0..7
        int d0 = dt * 64;
        // read: wave w handles d rows d0+w*16+i; lane reads float4 at col l*4 (1 KB/row, coalesced)
        #pragma unroll
        for (int i = 0; i < 16; ++i) {
            int dl = w * 16 + i;
            fv4 v = __builtin_nontemporal_load(
                (const fv4*)&Wk[(size_t)(d0 + dl) * NLAB + g * 256 + l * 4]);
            tile[l * 4 + 0][dl] = f2bf(v.x);
            tile[l * 4 + 1][dl] = f2bf(v.y);
            tile[l * 4 + 2][dl] = f2bf(v.z);
            tile[l * 4 + 3][dl] = f2bf(v.w);
        }
        __syncthreads();
        // write: needed columns only, coalesced 128 B stores + fused norms^2
        int rend = offs_end[g];
        int rbeg = rend - cnt[g];
        for (int r = rbeg + w; r < rend; r += 4) {
            int v = srt_v[r];
            int col = v - g * 256;
            unsigned short h = tile[col][l];
            WT[(size_t)r * DDIM + d0 + l] = h;
            float f = bf2f(h);
            float ss = f * f;
            ss += __shfl_xor(ss, 1, 64);  ss += __shfl_xor(ss, 2, 64);
            ss += __shfl_xor(ss, 4, 64);  ss += __shfl_xor(ss, 8, 64);
            ss += __shfl_xor(ss, 16, 64); ss += __shfl_xor(ss, 32, 64);
            if (l == 0) atomicAdd(&norms2[r], ss);
        }
    }
}

// ---------------- main2: fused [neg MFMA GEMM] and [pos dots] ----------------
static __device__ __forceinline__ float score_of(float acc, float nn) {
    float dot = acc / nn;
    dot = fminf(fmaxf(dot, -0.999f), 0.999f);
    return dot * dot / fmaxf(CV - 2.f * dot, EPSV);
}

__global__ __launch_bounds__(256) void main2_kernel(const unsigned short* __restrict__ qbf,
                                                    const float* __restrict__ query,
                                                    const unsigned short* __restrict__ WT,
                                                    const int* __restrict__ rank,
                                                    const float* __restrict__ norms2,
                                                    float* __restrict__ pos_scores,
                                                    float* __restrict__ Zrow) {
    int t = threadIdx.x;
    int w = t >> 6, l = t & 63;
    if (blockIdx.x < (BDIM / 64) * (NNEG / 64)) {
        // ---- negatives: 64x64 tile via MFMA ----
        __shared__ float rowsum[64];
        int bx = blockIdx.x;
        int mt = bx & 15, nt = bx >> 4;
        int wm = w >> 1, wn = w & 1;
        int lr = l & 15, lg = l >> 4;
        int m0 = mt * 64 + wm * 32;
        int n0 = nt * 64 + wn * 32;
        if (t < 64) rowsum[t] = 0.f;
        __syncthreads();

        int rB0 = rank[NPOS + n0 + lr];
        int rB1 = rank[NPOS + n0 + 16 + lr];
        const unsigned short* a0p = qbf + (size_t)(m0 + lr) * DDIM + lg * 8;
        const unsigned short* a1p = qbf + (size_t)(m0 + 16 + lr) * DDIM + lg * 8;
        const unsigned short* b0p = WT + (size_t)rB0 * DDIM + lg * 8;
        const unsigned short* b1p = WT + (size_t)rB1 * DDIM + lg * 8;

        f4v acc00 = {0.f, 0.f, 0.f, 0.f}, acc01 = acc00, acc10 = acc00, acc11 = acc00;
        #pragma unroll
        for (int k0 = 0; k0 < DDIM; k0 += 32) {
            s8v a0 = *(const s8v*)(a0p + k0);
            s8v a1 = *(const s8v*)(a1p + k0);
            s8v b0 = *(const s8v*)(b0p + k0);
            s8v b1 = *(const s8v*)(b1p + k0);
            acc00 = __builtin_amdgcn_mfma_f32_16x16x32_bf16(a0, b0, acc00, 0, 0, 0);
            acc01 = __builtin_amdgcn_mfma_f32_16x16x32_bf16(a0, b1, acc01, 0, 0, 0);
            acc10 = __builtin_amdgcn_mfma_f32_16x16x32_bf16(a1, b0, acc10, 0, 0, 0);
            acc11 = __builtin_amdgcn_mfma_f32_16x16x32_bf16(a1, b1, acc11, 0, 0, 0);
        }

        float nn0 = fmaxf(sqrtf(norms2[rB0]), 1e-4f);
        float nn1 = fmaxf(sqrtf(norms2[rB1]), 1e-4f);
        float s[8];
        #pragma unroll
        for (int i = 0; i < 4; ++i) {
            s[i]     = score_of(acc00[i], nn0) + score_of(acc01[i], nn1);
            s[4 + i] = score_of(acc10[i], nn0) + score_of(acc11[i], nn1);
        }
        #pragma unroll
        for (int i = 0; i < 8; ++i) {
            s[i] += __shfl_xor(s[i], 1, 64);
            s[i] += __shfl_xor(s[i], 2, 64);
            s[i] += __shfl_xor(s[i], 4, 64);
            s[i] += __shfl_xor(s[i], 8, 64);
        }
        if (lr == 0) {
            #pragma unroll
            for (int i = 0; i < 4; ++i) {
                atomicAdd(&rowsum[wm * 32 + lg * 4 + i], s[i]);
                atomicAdd(&rowsum[wm * 32 + 16 + lg * 4 + i], s[4 + i]);
            }
        }
        __syncthreads();
        if (t < 64) atomicAdd(&Zrow[mt * 64 + t], rowsum[t]);
    } else {
        // ---- positives: wave handles one b (16 j) ----
        int px = blockIdx.x - (BDIM / 64) * (NNEG / 64);
        int b = px * 4 + w;
        int j = b * KDIM + (l & 15);
        int r = rank[j];
        int g = l >> 4;
        const unsigned short* wrow = WT + (size_t)r * DDIM + g * 128;
        const float* qrow = query + (size_t)b * DDIM + g * 128;
        float acc = 0.f;
        #pragma unroll
        for (int kk = 0; kk < 128; kk += 8) {
            ushort4 w0 = *(const ushort4*)&wrow[kk];
            ushort4 w1 = *(const ushort4*)&wrow[kk + 4];
            float4 q0 = *(const float4*)&qrow[kk];
            float4 q1 = *(const float4*)&qrow[kk + 4];
            acc += bf2f(w0.x) * q0.x + bf2f(w0.y) * q0.y + bf2f(w0.z) * q0.z + bf2f(w0.w) * q0.w
                 + bf2f(w1.x) * q1.x + bf2f(w1.y) * q1.y + bf2f(w1.z) * q1.z + bf2f(w1.w) * q1.w;
        }
        acc += __shfl_xor(acc, 16, 64);
        acc += __shfl_xor(acc, 32, 64);
        if (l < 16) {
            float nrm = fmaxf(sqrtf(norms2[r]), 1e-4f);
            float dot = fminf(fmaxf(acc / nrm, -0.999f), 0.999f);
            float sc = dot * dot / fmaxf(CV - 2.f * dot, EPSV);
            pos_scores[j] = sc;
            float s = sc;
            s += __shfl_xor(s, 1, 64); s += __shfl_xor(s, 2, 64);
            s += __shfl_xor(s, 4, 64); s += __shfl_xor(s, 8, 64);
            if (l == 0) atomicAdd(&Zrow[b], s);
        }
    }
}

// ---------------- finalize (+writeout via ticket) ----------------
__global__ __launch_bounds__(256) void finalize_kernel(const float* __restrict__ pos_scores,
                                                       const float* __restrict__ label_mask,
                                                       const float* __restrict__ Zrow,
                                                       float* __restrict__ accum,
                                                       int* __restrict__ ticket,
                                                       float* __restrict__ out) {
    int j = blockIdx.x * 256 + threadIdx.x;
    int b = j >> 4;
    float lm = label_mask[j];
    float logZ = logf(Zrow[b] + (float)(KDIM + NNEG) * 1e-8f);
    float v = lm * (logf(pos_scores[j] + 1e-8f) - logZ);
    #pragma unroll
    for (int off = 32; off > 0; off >>= 1) {
        v  += __shfl_down(v, off, 64);
        lm += __shfl_down(lm, off, 64);
    }
    __shared__ float rv[4], rl[4];
    int wid = threadIdx.x >> 6, lane = threadIdx.x & 63;
    if (lane == 0) { rv[wid] = v; rl[wid] = lm; }
    __syncthreads();
    if (threadIdx.x == 0) {
        atomicAdd(&accum[0], rv[0] + rv[1] + rv[2] + rv[3]);
        atomicAdd(&accum[1], rl[0] + rl[1] + rl[2] + rl[3]);
        __threadfence();
        int old = atomicAdd(ticket, 1);
        if (old == (int)gridDim.x - 1) {
            float a = atomicAdd(&accum[0], 0.f);
            float m = atomicAdd(&accum[1], 0.f);
            out[0] = -a / (m + 1e-6f);
        }
    }
}

extern "C" void kernel_launch(void* const* d_in, const int* in_sizes, int n_in,
                              void* d_out, int out_size, void* d_ws, size_t ws_size,
                              hipStream_t stream) {
    const int*   indices    = (const int*)  d_in[0];
    const float* mask       = (const float*)d_in[1];
    const int*   labels     = (const int*)  d_in[2];
    const float* label_mask = (const float*)d_in[3];
    const int*   negs       = (const int*)  d_in[4];
    const float* embed      = (const float*)d_in[5];
    const float* Wk         = (const float*)d_in[6];
    float* out = (float*)d_out;

    // workspace layout (~25 MB)
    unsigned short* WT  = (unsigned short*)d_ws;                    // NSUB*DDIM bf16
    float* query      = (float*)(WT + (size_t)NSUB * DDIM);         // BDIM*DDIM f32
    unsigned short* qbf = (unsigned short*)(query + (size_t)BDIM * DDIM); // BDIM*DDIM bf16
    int*   all_idx    = (int*)(qbf + (size_t)BDIM * DDIM);          // NSUB
    int*   srt_v      = all_idx + NSUB;                             // NSUB
    int*   rank       = srt_v + NSUB;                               // NSUB
    float* norms2     = (float*)(rank + NSUB);                      // NSUB
    float* pos_scores = norms2 + NSUB;                              // NPOS
    float* Zrow       = pos_scores + NPOS;                          // BDIM
    float* accum      = Zrow + BDIM;                                // 2
    int*   ticket     = (int*)(accum + 2);                          // 1
    int*   cnt        = ticket + 1;                                 // NBUCK
    int*   offs       = cnt + NBUCK;                                // NBUCK

    init_kernel<<<NSUB / 256, 256, 0, stream>>>(cnt, norms2, Zrow, accum, ticket);
    count_kernel<<<NSUB / 256, 256, 0, stream>>>(labels, negs, all_idx, cnt);
    scan_kernel<<<1, 256, 0, stream>>>(cnt, offs);
    place_kernel<<<NSUB / 256, 256, 0, stream>>>(all_idx, offs, srt_v, rank);
    main1_kernel<<<BDIM + GT_BLOCKS, 256, 0, stream>>>(Wk, srt_v, offs, cnt, WT, norms2,
                                                       indices, mask, embed, query, qbf);
    main2_kernel<<<(BDIM / 64) * (NNEG / 64) + NPOS / 64, 256, 0, stream>>>(
        qbf, query, WT, rank, norms2, pos_scores, Zrow);
    finalize_kernel<<<NPOS / 256, 256, 0, stream>>>(pos_scores, label_mask, Zrow,
                                                    accum, ticket, out);
}